// Round 1
// baseline (1076.138 us; speedup 1.0000x reference)
//
#include <hip/hip_runtime.h>

typedef float f32x4 __attribute__((ext_vector_type(4)));
typedef __bf16 bf16x8 __attribute__((ext_vector_type(8)));
typedef __bf16 bf16x4 __attribute__((ext_vector_type(4)));

#define MFMA_BF16(a, b, c) __builtin_amdgcn_mfma_f32_16x16x32_bf16((a), (b), (c), 0, 0, 0)

typedef const __attribute__((address_space(1))) void* as1_cvp;
typedef __attribute__((address_space(3))) void* as3_vp;

__device__ __forceinline__ void gload_lds16(const __bf16* g, __bf16* l) {
  __builtin_amdgcn_global_load_lds((as1_cvp)g, (as3_vp)l, 16, 0, 0);
}

// ---------------- f32 -> bf16 convert ----------------
__global__ void cvt_kernel(const float* __restrict__ src, __bf16* __restrict__ dst, int n8) {
  int i = blockIdx.x * blockDim.x + threadIdx.x;
  if (i < n8) {
    f32x4 a = *(const f32x4*)(src + (size_t)i * 8);
    f32x4 b = *(const f32x4*)(src + (size_t)i * 8 + 4);
    bf16x8 o = {(__bf16)a[0], (__bf16)a[1], (__bf16)a[2], (__bf16)a[3],
                (__bf16)b[0], (__bf16)b[1], (__bf16)b[2], (__bf16)b[3]};
    *(bf16x8*)(dst + (size_t)i * 8) = o;
  }
}

// ---------------- C = A[M,1024] @ B[1024,1024]^T, bf16 in, OutT out ----------------
template <typename OutT>
__global__ __launch_bounds__(256) void gemm_bt_kernel(const __bf16* __restrict__ A,
                                                      const __bf16* __restrict__ B,
                                                      OutT* __restrict__ C) {
  __shared__ __attribute__((aligned(16))) __bf16 lA[128 * 32];
  __shared__ __attribute__((aligned(16))) __bf16 lB[128 * 32];
  const int t = threadIdx.x;
  const int m0 = blockIdx.x * 128, n0 = blockIdx.y * 128;
  const int lane = t & 63, w = t >> 6;
  const int wm = w >> 1, wn = w & 1;
  const int lrow = lane & 15, quad = lane >> 4;
  const f32x4 z4 = {0.f, 0.f, 0.f, 0.f};
  f32x4 acc[4][4];
#pragma unroll
  for (int i = 0; i < 4; ++i)
#pragma unroll
    for (int j = 0; j < 4; ++j) acc[i][j] = z4;
  for (int k0 = 0; k0 < 1024; k0 += 32) {
    __syncthreads();
#pragma unroll
    for (int rr = 0; rr < 2; ++rr) {
      int elem = rr * 2048 + t * 8;
      int row = elem >> 5, col = elem & 31;
      gload_lds16(A + (size_t)(m0 + row) * 1024 + k0 + col, lA + elem);
      gload_lds16(B + (size_t)(n0 + row) * 1024 + k0 + col, lB + elem);
    }
    __syncthreads();
    bf16x8 af[4], bg[4];
#pragma unroll
    for (int i = 0; i < 4; ++i)
      af[i] = *(const bf16x8*)(lA + (wm * 64 + i * 16 + lrow) * 32 + quad * 8);
#pragma unroll
    for (int j = 0; j < 4; ++j)
      bg[j] = *(const bf16x8*)(lB + (wn * 64 + j * 16 + lrow) * 32 + quad * 8);
#pragma unroll
    for (int i = 0; i < 4; ++i)
#pragma unroll
      for (int j = 0; j < 4; ++j) acc[i][j] = MFMA_BF16(af[i], bg[j], acc[i][j]);
  }
#pragma unroll
  for (int i = 0; i < 4; ++i) {
    int grow = m0 + wm * 64 + i * 16 + quad * 4;
#pragma unroll
    for (int j = 0; j < 4; ++j) {
      int gcol = n0 + wn * 64 + j * 16 + lrow;
#pragma unroll
      for (int r = 0; r < 4; ++r) C[(size_t)(grow + r) * 1024 + gcol] = (OutT)acc[i][j][r];
    }
  }
}

// ---------------- Vp[8192,1024] -> Vt: Vt[(m&~1023)+n][m&1023] = Vp[m][n] ----------------
__global__ __launch_bounds__(256) void transpose_v(const __bf16* __restrict__ Vp,
                                                   __bf16* __restrict__ Vt) {
  __shared__ __bf16 tile[64][65];
  int b = blockIdx.z;
  int i = blockIdx.x, j = blockIdx.y;  // i: s-tile, j: n-tile
  int t = threadIdx.x;
#pragma unroll
  for (int it = 0; it < 2; ++it) {
    int r = it * 32 + (t >> 3);
    int c = (t & 7) * 8;
    bf16x8 v = *(const bf16x8*)(Vp + (size_t)(b * 1024 + i * 64 + r) * 1024 + j * 64 + c);
#pragma unroll
    for (int u = 0; u < 8; ++u) tile[r][c + u] = v[u];
  }
  __syncthreads();
#pragma unroll
  for (int it = 0; it < 2; ++it) {
    int r = it * 32 + (t >> 3);  // n index
    int c = (t & 7) * 8;         // s base
    bf16x8 o;
#pragma unroll
    for (int u = 0; u < 8; ++u) o[u] = tile[c + u][r];
    *(bf16x8*)(Vt + (size_t)(b * 1024 + j * 64 + r) * 1024 + i * 64 + c) = o;
  }
}

// ---------------- stage a 128x64 tile (row stride 1024) into [2][128][32] panels ----------------
__device__ __forceinline__ void stage_tile_64(const __bf16* gbase, __bf16* lds, int t) {
#pragma unroll
  for (int p = 0; p < 2; ++p) {
#pragma unroll
    for (int rr = 0; rr < 2; ++rr) {
      int elem = rr * 2048 + t * 8;
      int row = elem >> 5, col = elem & 31;
      gload_lds16(gbase + (size_t)row * 1024 + p * 32 + col, lds + p * 4096 + elem);
    }
  }
}

// ---------------- scores + softmax + attn write (causal), per (bh, qt) ----------------
__global__ __launch_bounds__(256) void attn_kernel(const __bf16* __restrict__ Qp,
                                                   const __bf16* __restrict__ Kp,
                                                   float* __restrict__ attn) {
  __shared__ __attribute__((aligned(16))) __bf16 lQ[2 * 128 * 32];
  __shared__ __attribute__((aligned(16))) __bf16 lK[2 * 128 * 32];
  __shared__ float red[2][2][128];
  __shared__ float finm[128], finr[128];
  const int qt = 7 - (int)blockIdx.x;  // longest blocks first
  const int bh = blockIdx.y;
  const int b = bh >> 4, h = bh & 15;
  const int t = threadIdx.x, lane = t & 63, w = t >> 6;
  const int wm = w >> 1, wn = w & 1, lrow = lane & 15, quad = lane >> 4;
  const __bf16* qbase = Qp + (size_t)(b * 1024 + qt * 128) * 1024 + h * 64;
  const __bf16* kbase = Kp + (size_t)(b * 1024) * 1024 + h * 64;
  float* abase = attn + (size_t)bh * 1024 * 1024;
  const f32x4 z4 = {0.f, 0.f, 0.f, 0.f};

  stage_tile_64(qbase, lQ, t);

  float m_run[4][4], l_run[4][4];
#pragma unroll
  for (int i = 0; i < 4; ++i)
#pragma unroll
    for (int r = 0; r < 4; ++r) { m_run[i][r] = -1e30f; l_run[i][r] = 0.f; }

  // ---- phase 1: row max + denom (online) ----
  for (int kt = 0; kt <= qt; ++kt) {
    __syncthreads();
    stage_tile_64(kbase + (size_t)(kt * 128) * 1024, lK, t);
    __syncthreads();
    f32x4 acc[4][4];
#pragma unroll
    for (int i = 0; i < 4; ++i)
#pragma unroll
      for (int j = 0; j < 4; ++j) acc[i][j] = z4;
#pragma unroll
    for (int ks = 0; ks < 2; ++ks) {
      bf16x8 af[4], bg[4];
#pragma unroll
      for (int i = 0; i < 4; ++i)
        af[i] = *(const bf16x8*)(lQ + ks * 4096 + (wm * 64 + i * 16 + lrow) * 32 + quad * 8);
#pragma unroll
      for (int j = 0; j < 4; ++j)
        bg[j] = *(const bf16x8*)(lK + ks * 4096 + (wn * 64 + j * 16 + lrow) * 32 + quad * 8);
#pragma unroll
      for (int i = 0; i < 4; ++i)
#pragma unroll
        for (int j = 0; j < 4; ++j) acc[i][j] = MFMA_BF16(af[i], bg[j], acc[i][j]);
    }
    const bool diag = (kt == qt);
#pragma unroll
    for (int i = 0; i < 4; ++i) {
#pragma unroll
      for (int r = 0; r < 4; ++r) {
        int qrow = qt * 128 + wm * 64 + i * 16 + quad * 4 + r;
        float s[4];
        float mx = -1e30f;
#pragma unroll
        for (int j = 0; j < 4; ++j) {
          float v = acc[i][j][r] * 0.0625f;  // / SCALE(=16)
          v = fminf(fmaxf(v, -30.f), 30.f);
          if (diag) {
            int kcol = kt * 128 + wn * 64 + j * 16 + lrow;
            if (kcol > qrow) v = -1e30f;
          }
          s[j] = v;
          mx = fmaxf(mx, v);
        }
        mx = fmaxf(mx, __shfl_xor(mx, 1));
        mx = fmaxf(mx, __shfl_xor(mx, 2));
        mx = fmaxf(mx, __shfl_xor(mx, 4));
        mx = fmaxf(mx, __shfl_xor(mx, 8));
        float sum = 0.f;
#pragma unroll
        for (int j = 0; j < 4; ++j) sum += (s[j] > -1e29f) ? __expf(s[j] - mx) : 0.f;
        sum += __shfl_xor(sum, 1);
        sum += __shfl_xor(sum, 2);
        sum += __shfl_xor(sum, 4);
        sum += __shfl_xor(sum, 8);
        float mo = m_run[i][r];
        float mn = fmaxf(mo, mx);
        l_run[i][r] = l_run[i][r] * __expf(mo - mn) + sum * __expf(mx - mn);
        m_run[i][r] = mn;
      }
    }
  }

  // ---- cross-wave (wn) merge ----
  if (lrow == 0) {
#pragma unroll
    for (int i = 0; i < 4; ++i)
#pragma unroll
      for (int r = 0; r < 4; ++r) {
        int row = wm * 64 + i * 16 + quad * 4 + r;
        red[wn][0][row] = m_run[i][r];
        red[wn][1][row] = l_run[i][r];
      }
  }
  __syncthreads();
  if (t < 128) {
    float m0 = red[0][0][t], l0 = red[0][1][t];
    float m1 = red[1][0][t], l1 = red[1][1][t];
    float mf = fmaxf(m0, m1);
    float lf = l0 * __expf(m0 - mf) + l1 * __expf(m1 - mf);
    finm[t] = mf;
    finr[t] = 1.0f / lf;
  }
  __syncthreads();
  float mf[4][4], rf[4][4];
#pragma unroll
  for (int i = 0; i < 4; ++i)
#pragma unroll
    for (int r = 0; r < 4; ++r) {
      int row = wm * 64 + i * 16 + quad * 4 + r;
      mf[i][r] = finm[row];
      rf[i][r] = finr[row];
    }

  // ---- phase 2: recompute, normalize, write attn ----
  for (int kt = 0; kt <= qt; ++kt) {
    __syncthreads();
    stage_tile_64(kbase + (size_t)(kt * 128) * 1024, lK, t);
    __syncthreads();
    f32x4 acc[4][4];
#pragma unroll
    for (int i = 0; i < 4; ++i)
#pragma unroll
      for (int j = 0; j < 4; ++j) acc[i][j] = z4;
#pragma unroll
    for (int ks = 0; ks < 2; ++ks) {
      bf16x8 af[4], bg[4];
#pragma unroll
      for (int i = 0; i < 4; ++i)
        af[i] = *(const bf16x8*)(lQ + ks * 4096 + (wm * 64 + i * 16 + lrow) * 32 + quad * 8);
#pragma unroll
      for (int j = 0; j < 4; ++j)
        bg[j] = *(const bf16x8*)(lK + ks * 4096 + (wn * 64 + j * 16 + lrow) * 32 + quad * 8);
#pragma unroll
      for (int i = 0; i < 4; ++i)
#pragma unroll
        for (int j = 0; j < 4; ++j) acc[i][j] = MFMA_BF16(af[i], bg[j], acc[i][j]);
    }
    const bool diag = (kt == qt);
#pragma unroll
    for (int i = 0; i < 4; ++i) {
#pragma unroll
      for (int j = 0; j < 4; ++j) {
        int kcol = kt * 128 + wn * 64 + j * 16 + lrow;
#pragma unroll
        for (int r = 0; r < 4; ++r) {
          int qrow = qt * 128 + wm * 64 + i * 16 + quad * 4 + r;
          float v = acc[i][j][r] * 0.0625f;
          v = fminf(fmaxf(v, -30.f), 30.f);
          float p;
          if (diag && kcol > qrow)
            p = 0.f;
          else
            p = __expf(v - mf[i][r]) * rf[i][r];
          abase[(size_t)qrow * 1024 + kcol] = p;
        }
      }
    }
  }

  // ---- zero-fill masked column range ----
  int zc = (7 - qt) * 128;
  if (zc > 0) {
    int rpr = zc >> 2;  // float4 per row
    int n4 = 128 * rpr;
    for (int idx = t; idx < n4; idx += 256) {
      int row = idx / rpr;
      int c4 = idx - row * rpr;
      *(f32x4*)(abase + (size_t)(qt * 128 + row) * 1024 + (qt + 1) * 128 + c4 * 4) = z4;
    }
  }
}

// ---------------- context = attn @ V per (bh, qt): [128 x 64] output ----------------
__global__ __launch_bounds__(256) void ctx_kernel(const float* __restrict__ attn,
                                                  const __bf16* __restrict__ Vt,
                                                  __bf16* __restrict__ ctx) {
  __shared__ __attribute__((aligned(16))) __bf16 lA[128 * 32];
  __shared__ __attribute__((aligned(16))) __bf16 lV[64 * 32];
  const int qt = 7 - (int)blockIdx.x;
  const int bh = blockIdx.y;
  const int b = bh >> 4, h = bh & 15;
  const int t = threadIdx.x, lane = t & 63, w = t >> 6;
  const int wm = w >> 1, wn = w & 1, lrow = lane & 15, quad = lane >> 4;
  const float* abase = attn + (size_t)bh * 1024 * 1024 + (size_t)(qt * 128) * 1024;
  const __bf16* vbase = Vt + (size_t)(b * 1024 + h * 64) * 1024;
  const f32x4 z4 = {0.f, 0.f, 0.f, 0.f};
  f32x4 acc[4][2];
#pragma unroll
  for (int i = 0; i < 4; ++i)
#pragma unroll
    for (int j = 0; j < 2; ++j) acc[i][j] = z4;
  const int kmax = (qt + 1) * 128;
  for (int k0 = 0; k0 < kmax; k0 += 32) {
    __syncthreads();
    // stage attn tile 128x32 (f32 -> bf16)
#pragma unroll
    for (int qq = 0; qq < 4; ++qq) {
      int lin4 = qq * 256 + t;
      int row = lin4 >> 3, c4 = lin4 & 7;
      f32x4 v = *(const f32x4*)(abase + (size_t)row * 1024 + k0 + c4 * 4);
      bf16x4 o = {(__bf16)v[0], (__bf16)v[1], (__bf16)v[2], (__bf16)v[3]};
      *(bf16x4*)(lA + row * 32 + c4 * 4) = o;
    }
    // stage Vt tile 64x32 via global_load_lds
    {
      int elem = t * 8;
      int vrow = elem >> 5, vcol = elem & 31;
      gload_lds16(vbase + (size_t)vrow * 1024 + k0 + vcol, lV + elem);
    }
    __syncthreads();
    bf16x8 af[4], bg[2];
#pragma unroll
    for (int i = 0; i < 4; ++i)
      af[i] = *(const bf16x8*)(lA + (wm * 64 + i * 16 + lrow) * 32 + quad * 8);
#pragma unroll
    for (int j = 0; j < 2; ++j)
      bg[j] = *(const bf16x8*)(lV + (wn * 32 + j * 16 + lrow) * 32 + quad * 8);
#pragma unroll
    for (int i = 0; i < 4; ++i)
#pragma unroll
      for (int j = 0; j < 2; ++j) acc[i][j] = MFMA_BF16(af[i], bg[j], acc[i][j]);
  }
#pragma unroll
  for (int i = 0; i < 4; ++i) {
    int grow = b * 1024 + qt * 128 + wm * 64 + i * 16 + quad * 4;
#pragma unroll
    for (int j = 0; j < 2; ++j) {
      int gcol = h * 64 + wn * 32 + j * 16 + lrow;
#pragma unroll
      for (int r = 0; r < 4; ++r) ctx[(size_t)(grow + r) * 1024 + gcol] = (__bf16)acc[i][j][r];
    }
  }
}

extern "C" void kernel_launch(void* const* d_in, const int* in_sizes, int n_in,
                              void* d_out, int out_size, void* d_ws, size_t ws_size,
                              hipStream_t stream) {
  const float* q = (const float*)d_in[0];
  const float* k = (const float*)d_in[1];
  const float* v = (const float*)d_in[2];
  // d_in[3] = mask (guaranteed tril; causal handled analytically)
  const float* Wq = (const float*)d_in[4];
  const float* Wk = (const float*)d_in[5];
  const float* Wv = (const float*)d_in[6];
  const float* Wo = (const float*)d_in[7];
  float* out = (float*)d_out;
  float* attn = out + 8388608;  // [B,H,S,S] region of d_out

  __bf16* ws = (__bf16*)d_ws;
  __bf16* qb = ws;                   // 8M elems
  __bf16* kb = ws + 8388608;         // 8M
  __bf16* vb = ws + 16777216;        // 8M
  __bf16* wqb = ws + 25165824;       // 1M
  __bf16* wkb = ws + 26214400;       // 1M
  __bf16* wvb = ws + 27262976;       // 1M
  __bf16* wob = ws + 28311552;       // 1M
  __bf16* Qp = ws + 29360128;        // 8M
  __bf16* Kp = ws + 37748736;        // 8M
  __bf16* Vp = ws + 46137344;        // 8M  (end: 54.5M elems = 104 MB)
  __bf16* Vt = qb;   // alias: qb dead after Q projection
  __bf16* ctx = kb;  // alias: kb dead after K projection

  cvt_kernel<<<4096, 256, 0, stream>>>(q, qb, 1048576);
  cvt_kernel<<<4096, 256, 0, stream>>>(k, kb, 1048576);
  cvt_kernel<<<4096, 256, 0, stream>>>(v, vb, 1048576);
  cvt_kernel<<<512, 256, 0, stream>>>(Wq, wqb, 131072);
  cvt_kernel<<<512, 256, 0, stream>>>(Wk, wkb, 131072);
  cvt_kernel<<<512, 256, 0, stream>>>(Wv, wvb, 131072);
  cvt_kernel<<<512, 256, 0, stream>>>(Wo, wob, 131072);

  dim3 gg(64, 8);
  gemm_bt_kernel<__bf16><<<gg, 256, 0, stream>>>(qb, wqb, Qp);
  gemm_bt_kernel<__bf16><<<gg, 256, 0, stream>>>(kb, wkb, Kp);
  gemm_bt_kernel<__bf16><<<gg, 256, 0, stream>>>(vb, wvb, Vp);

  transpose_v<<<dim3(16, 16, 8), 256, 0, stream>>>(Vp, Vt);

  attn_kernel<<<dim3(8, 128), 256, 0, stream>>>(Qp, Kp, attn);
  ctx_kernel<<<dim3(8, 128), 256, 0, stream>>>(attn, Vt, ctx);

  gemm_bt_kernel<float><<<gg, 256, 0, stream>>>(ctx, wob, out);
}

// Round 2
// 862.549 us; speedup vs baseline: 1.2476x; 1.2476x over previous
//
#include <hip/hip_runtime.h>

typedef float f32x4 __attribute__((ext_vector_type(4)));
typedef __bf16 bf16x8 __attribute__((ext_vector_type(8)));
typedef __bf16 bf16x4 __attribute__((ext_vector_type(4)));

#define MFMA_BF16(a, b, c) __builtin_amdgcn_mfma_f32_16x16x32_bf16((a), (b), (c), 0, 0, 0)

typedef const __attribute__((address_space(1))) void* as1_cvp;
typedef __attribute__((address_space(3))) void* as3_vp;

__device__ __forceinline__ void gload_lds16(const __bf16* g, __bf16* l) {
  __builtin_amdgcn_global_load_lds((as1_cvp)g, (as3_vp)l, 16, 0, 0);
}

// ---------------- f32 -> bf16 converts (fused launches) ----------------
__global__ void cvt3_kernel(const float* __restrict__ s0, const float* __restrict__ s1,
                            const float* __restrict__ s2, __bf16* __restrict__ d0,
                            __bf16* __restrict__ d1, __bf16* __restrict__ d2) {
  int y = blockIdx.y;
  const float* src = (y == 0) ? s0 : (y == 1) ? s1 : s2;
  __bf16* dst = (y == 0) ? d0 : (y == 1) ? d1 : d2;
  size_t i = ((size_t)blockIdx.x * 256 + threadIdx.x) * 8;
  f32x4 a = *(const f32x4*)(src + i);
  f32x4 b = *(const f32x4*)(src + i + 4);
  bf16x8 o = {(__bf16)a[0], (__bf16)a[1], (__bf16)a[2], (__bf16)a[3],
              (__bf16)b[0], (__bf16)b[1], (__bf16)b[2], (__bf16)b[3]};
  *(bf16x8*)(dst + i) = o;
}

__global__ void cvt4_kernel(const float* __restrict__ s0, const float* __restrict__ s1,
                            const float* __restrict__ s2, const float* __restrict__ s3,
                            __bf16* __restrict__ d0, __bf16* __restrict__ d1,
                            __bf16* __restrict__ d2, __bf16* __restrict__ d3) {
  int y = blockIdx.y;
  const float* src = (y == 0) ? s0 : (y == 1) ? s1 : (y == 2) ? s2 : s3;
  __bf16* dst = (y == 0) ? d0 : (y == 1) ? d1 : (y == 2) ? d2 : d3;
  size_t i = ((size_t)blockIdx.x * 256 + threadIdx.x) * 8;
  f32x4 a = *(const f32x4*)(src + i);
  f32x4 b = *(const f32x4*)(src + i + 4);
  bf16x8 o = {(__bf16)a[0], (__bf16)a[1], (__bf16)a[2], (__bf16)a[3],
              (__bf16)b[0], (__bf16)b[1], (__bf16)b[2], (__bf16)b[3]};
  *(bf16x8*)(dst + i) = o;
}

// ---------------- C = A[8192,1024] @ B[1024,1024]^T, z-batched x3 ----------------
template <typename OutT>
__global__ __launch_bounds__(256) void gemm_bt_kernel(
    const __bf16* __restrict__ A0, const __bf16* __restrict__ B0, OutT* __restrict__ C0,
    const __bf16* __restrict__ A1, const __bf16* __restrict__ B1, OutT* __restrict__ C1,
    const __bf16* __restrict__ A2, const __bf16* __restrict__ B2, OutT* __restrict__ C2) {
  __shared__ __attribute__((aligned(16))) __bf16 lA[128 * 32];
  __shared__ __attribute__((aligned(16))) __bf16 lB[128 * 32];
  const int z = blockIdx.z;
  const __bf16* A = (z == 0) ? A0 : (z == 1) ? A1 : A2;
  const __bf16* B = (z == 0) ? B0 : (z == 1) ? B1 : B2;
  OutT* C = (z == 0) ? C0 : (z == 1) ? C1 : C2;
  const int t = threadIdx.x;
  const int m0 = blockIdx.x * 128, n0 = blockIdx.y * 128;
  const int lane = t & 63, w = t >> 6;
  const int wm = w >> 1, wn = w & 1;
  const int lrow = lane & 15, quad = lane >> 4;
  const f32x4 z4 = {0.f, 0.f, 0.f, 0.f};
  f32x4 acc[4][4];
#pragma unroll
  for (int i = 0; i < 4; ++i)
#pragma unroll
    for (int j = 0; j < 4; ++j) acc[i][j] = z4;
  for (int k0 = 0; k0 < 1024; k0 += 32) {
    __syncthreads();
#pragma unroll
    for (int rr = 0; rr < 2; ++rr) {
      int elem = rr * 2048 + t * 8;
      int row = elem >> 5, col = elem & 31;
      gload_lds16(A + (size_t)(m0 + row) * 1024 + k0 + col, lA + elem);
      gload_lds16(B + (size_t)(n0 + row) * 1024 + k0 + col, lB + elem);
    }
    __syncthreads();
    bf16x8 af[4], bg[4];
#pragma unroll
    for (int i = 0; i < 4; ++i)
      af[i] = *(const bf16x8*)(lA + (wm * 64 + i * 16 + lrow) * 32 + quad * 8);
#pragma unroll
    for (int j = 0; j < 4; ++j)
      bg[j] = *(const bf16x8*)(lB + (wn * 64 + j * 16 + lrow) * 32 + quad * 8);
#pragma unroll
    for (int i = 0; i < 4; ++i)
#pragma unroll
      for (int j = 0; j < 4; ++j) acc[i][j] = MFMA_BF16(af[i], bg[j], acc[i][j]);
  }
#pragma unroll
  for (int i = 0; i < 4; ++i) {
    int grow = m0 + wm * 64 + i * 16 + quad * 4;
#pragma unroll
    for (int j = 0; j < 4; ++j) {
      int gcol = n0 + wn * 64 + j * 16 + lrow;
#pragma unroll
      for (int r = 0; r < 4; ++r) C[(size_t)(grow + r) * 1024 + gcol] = (OutT)acc[i][j][r];
    }
  }
}

// ---------------- Vp[8192,1024] -> Vt: Vt[(m&~1023)+n][m&1023] = Vp[m][n] ----------------
__global__ __launch_bounds__(256) void transpose_v(const __bf16* __restrict__ Vp,
                                                   __bf16* __restrict__ Vt) {
  __shared__ __bf16 tile[64][65];
  int b = blockIdx.z;
  int i = blockIdx.x, j = blockIdx.y;
  int t = threadIdx.x;
#pragma unroll
  for (int it = 0; it < 2; ++it) {
    int r = it * 32 + (t >> 3);
    int c = (t & 7) * 8;
    bf16x8 v = *(const bf16x8*)(Vp + (size_t)(b * 1024 + i * 64 + r) * 1024 + j * 64 + c);
#pragma unroll
    for (int u = 0; u < 8; ++u) tile[r][c + u] = v[u];
  }
  __syncthreads();
#pragma unroll
  for (int it = 0; it < 2; ++it) {
    int r = it * 32 + (t >> 3);
    int c = (t & 7) * 8;
    bf16x8 o;
#pragma unroll
    for (int u = 0; u < 8; ++u) o[u] = tile[c + u][r];
    *(bf16x8*)(Vt + (size_t)(b * 1024 + j * 64 + r) * 1024 + i * 64 + c) = o;
  }
}

// ---------------- staging helpers ----------------
// 128 rows x 64 cols (row stride 1024) -> [2 panels][128][32]
__device__ __forceinline__ void stage_tile_64(const __bf16* gbase, __bf16* lds, int t) {
#pragma unroll
  for (int p = 0; p < 2; ++p) {
#pragma unroll
    for (int rr = 0; rr < 2; ++rr) {
      int elem = rr * 2048 + t * 8;
      int row = elem >> 5, col = elem & 31;
      gload_lds16(gbase + (size_t)row * 1024 + p * 32 + col, lds + p * 4096 + elem);
    }
  }
}

// 64 rows x 128 cols (row stride 1024) -> [4 panels][64][32]
__device__ __forceinline__ void stage_v_tile(const __bf16* gbase, __bf16* lds, int t) {
#pragma unroll
  for (int it = 0; it < 4; ++it) {
    int elem = (it * 256 + t) * 8;
    int p = elem >> 11;
    int rem = elem & 2047;
    int row = rem >> 5, col = rem & 31;
    gload_lds16(gbase + (size_t)row * 1024 + p * 32 + col, lds + elem);
  }
}

// ---------------- fused scores + softmax(fixed max=30) + attn write + PV ----------------
__global__ __launch_bounds__(256, 2) void attn_fused_kernel(const __bf16* __restrict__ Qp,
                                                            const __bf16* __restrict__ Kp,
                                                            const __bf16* __restrict__ Vt,
                                                            float* __restrict__ attn,
                                                            __bf16* __restrict__ ctx) {
  __shared__ __attribute__((aligned(16))) __bf16 lK[2 * 128 * 32];  // 16 KB
  __shared__ __attribute__((aligned(16))) __bf16 lV[4 * 64 * 32];   // 16 KB
  __shared__ __attribute__((aligned(16))) __bf16 lP[128 * 136];     // 34 KB (Q staging + P)
  __shared__ float red[2][128];
  __shared__ float finr[128];
  const int qt = 7 - (int)blockIdx.x;  // longest first
  const int bh = blockIdx.y;
  const int b = bh >> 4, h = bh & 15;
  const int t = threadIdx.x, lane = t & 63, w = t >> 6;
  const int wm = w >> 1, wn = w & 1, lrow = lane & 15, quad = lane >> 4;
  const __bf16* qbase = Qp + (size_t)(b * 1024 + qt * 128) * 1024 + h * 64;
  const __bf16* kbase = Kp + (size_t)(b * 1024) * 1024 + h * 64;
  const __bf16* vbase = Vt + (size_t)(b * 1024 + h * 64) * 1024;
  float* abase = attn + (size_t)bh * 1024 * 1024;
  const f32x4 z4 = {0.f, 0.f, 0.f, 0.f};

  // ---- stage Q once, keep fragments in registers ----
  stage_tile_64(qbase, lP, t);
  __syncthreads();
  bf16x8 qf[2][4];
#pragma unroll
  for (int ks = 0; ks < 2; ++ks)
#pragma unroll
    for (int i = 0; i < 4; ++i)
      qf[ks][i] = *(const bf16x8*)(lP + ks * 4096 + (wm * 64 + i * 16 + lrow) * 32 + quad * 8);

  // ---- phase 1: row denominators only (fixed max = 30, no shuffles in loop) ----
  float part[4][4];
#pragma unroll
  for (int i = 0; i < 4; ++i)
#pragma unroll
    for (int r = 0; r < 4; ++r) part[i][r] = 0.f;

  for (int kt = 0; kt <= qt; ++kt) {
    __syncthreads();
    stage_tile_64(kbase + (size_t)(kt * 128) * 1024, lK, t);
    __syncthreads();
    f32x4 acc[4][4];
#pragma unroll
    for (int i = 0; i < 4; ++i)
#pragma unroll
      for (int j = 0; j < 4; ++j) acc[i][j] = z4;
#pragma unroll
    for (int ks = 0; ks < 2; ++ks) {
      bf16x8 bg[4];
#pragma unroll
      for (int j = 0; j < 4; ++j)
        bg[j] = *(const bf16x8*)(lK + ks * 4096 + (wn * 64 + j * 16 + lrow) * 32 + quad * 8);
#pragma unroll
      for (int i = 0; i < 4; ++i)
#pragma unroll
        for (int j = 0; j < 4; ++j) acc[i][j] = MFMA_BF16(qf[ks][i], bg[j], acc[i][j]);
    }
    const bool diag = (kt == qt);
#pragma unroll
    for (int i = 0; i < 4; ++i) {
#pragma unroll
      for (int j = 0; j < 4; ++j) {
        int kcol = wn * 64 + j * 16 + lrow;
#pragma unroll
        for (int r = 0; r < 4; ++r) {
          int qrow = wm * 64 + i * 16 + quad * 4 + r;
          float v = acc[i][j][r] * 0.0625f;
          v = fminf(fmaxf(v, -30.f), 30.f);
          float e = __expf(v - 30.f);
          if (!(diag && kcol > qrow)) part[i][r] += e;
        }
      }
    }
  }
  // one reduction at the end: sum across the 16 lanes of each row group
#pragma unroll
  for (int i = 0; i < 4; ++i)
#pragma unroll
    for (int r = 0; r < 4; ++r) {
      float s = part[i][r];
      s += __shfl_xor(s, 1);
      s += __shfl_xor(s, 2);
      s += __shfl_xor(s, 4);
      s += __shfl_xor(s, 8);
      part[i][r] = s;
    }
  if (lrow == 0) {
#pragma unroll
    for (int i = 0; i < 4; ++i)
#pragma unroll
      for (int r = 0; r < 4; ++r) red[wn][wm * 64 + i * 16 + quad * 4 + r] = part[i][r];
  }
  __syncthreads();
  if (t < 128) finr[t] = 1.0f / (red[0][t] + red[1][t]);
  __syncthreads();
  float rf[4][4];
#pragma unroll
  for (int i = 0; i < 4; ++i)
#pragma unroll
    for (int r = 0; r < 4; ++r) rf[i][r] = finr[wm * 64 + i * 16 + quad * 4 + r];

  // ---- phase 2: recompute scores, write normalized attn, fused PV ----
  f32x4 accp[4][2];
#pragma unroll
  for (int i = 0; i < 4; ++i)
#pragma unroll
    for (int j = 0; j < 2; ++j) accp[i][j] = z4;

  for (int kt = 0; kt <= qt; ++kt) {
    __syncthreads();
    stage_tile_64(kbase + (size_t)(kt * 128) * 1024, lK, t);
    stage_v_tile(vbase + kt * 128, lV, t);
    __syncthreads();
    f32x4 acc[4][4];
#pragma unroll
    for (int i = 0; i < 4; ++i)
#pragma unroll
      for (int j = 0; j < 4; ++j) acc[i][j] = z4;
#pragma unroll
    for (int ks = 0; ks < 2; ++ks) {
      bf16x8 bg[4];
#pragma unroll
      for (int j = 0; j < 4; ++j)
        bg[j] = *(const bf16x8*)(lK + ks * 4096 + (wn * 64 + j * 16 + lrow) * 32 + quad * 8);
#pragma unroll
      for (int i = 0; i < 4; ++i)
#pragma unroll
        for (int j = 0; j < 4; ++j) acc[i][j] = MFMA_BF16(qf[ks][i], bg[j], acc[i][j]);
    }
    const bool diag = (kt == qt);
#pragma unroll
    for (int i = 0; i < 4; ++i) {
#pragma unroll
      for (int j = 0; j < 4; ++j) {
        int kcol = wn * 64 + j * 16 + lrow;
#pragma unroll
        for (int r = 0; r < 4; ++r) {
          int qrow = wm * 64 + i * 16 + quad * 4 + r;
          float v = acc[i][j][r] * 0.0625f;
          v = fminf(fmaxf(v, -30.f), 30.f);
          float p = (diag && kcol > qrow) ? 0.f : __expf(v - 30.f) * rf[i][r];
          abase[(size_t)(qt * 128 + qrow) * 1024 + kt * 128 + kcol] = p;
          lP[qrow * 136 + kcol] = (__bf16)p;
        }
      }
    }
    __syncthreads();
    // PV: ctx[128 x 64] += P[128 x 128] @ V^T[64 x 128]^T
#pragma unroll
    for (int ks2 = 0; ks2 < 4; ++ks2) {
      bf16x8 af[4], bg[2];
#pragma unroll
      for (int i = 0; i < 4; ++i)
        af[i] = *(const bf16x8*)(lP + (wm * 64 + i * 16 + lrow) * 136 + ks2 * 32 + quad * 8);
#pragma unroll
      for (int j = 0; j < 2; ++j)
        bg[j] = *(const bf16x8*)(lV + ks2 * 2048 + (wn * 32 + j * 16 + lrow) * 32 + quad * 8);
#pragma unroll
      for (int i = 0; i < 4; ++i)
#pragma unroll
        for (int j = 0; j < 2; ++j) accp[i][j] = MFMA_BF16(af[i], bg[j], accp[i][j]);
    }
  }

  // ---- zero-fill masked columns ----
  int zc = (7 - qt) * 128;
  if (zc > 0) {
    int rpr = zc >> 2;
    int n4 = 128 * rpr;
    for (int idx = t; idx < n4; idx += 256) {
      int row = idx / rpr;
      int c4 = idx - row * rpr;
      *(f32x4*)(abase + (size_t)(qt * 128 + row) * 1024 + (qt + 1) * 128 + c4 * 4) = z4;
    }
  }

  // ---- ctx epilogue ----
#pragma unroll
  for (int i = 0; i < 4; ++i) {
    int grow = b * 1024 + qt * 128 + wm * 64 + i * 16 + quad * 4;
#pragma unroll
    for (int j = 0; j < 2; ++j) {
      int gcol = h * 64 + wn * 32 + j * 16 + lrow;
#pragma unroll
      for (int r = 0; r < 4; ++r) ctx[(size_t)(grow + r) * 1024 + gcol] = (__bf16)accp[i][j][r];
    }
  }
}

extern "C" void kernel_launch(void* const* d_in, const int* in_sizes, int n_in,
                              void* d_out, int out_size, void* d_ws, size_t ws_size,
                              hipStream_t stream) {
  const float* q = (const float*)d_in[0];
  const float* k = (const float*)d_in[1];
  const float* v = (const float*)d_in[2];
  const float* Wq = (const float*)d_in[4];
  const float* Wk = (const float*)d_in[5];
  const float* Wv = (const float*)d_in[6];
  const float* Wo = (const float*)d_in[7];
  float* out = (float*)d_out;
  float* attn = out + 8388608;

  __bf16* ws = (__bf16*)d_ws;
  __bf16* qb = ws;
  __bf16* kb = ws + 8388608;
  __bf16* vb = ws + 16777216;
  __bf16* wqb = ws + 25165824;
  __bf16* wkb = ws + 26214400;
  __bf16* wvb = ws + 27262976;
  __bf16* wob = ws + 28311552;
  __bf16* Qp = ws + 29360128;
  __bf16* Kp = ws + 37748736;
  __bf16* Vp = ws + 46137344;
  __bf16* Vt = qb;   // qb dead after projections
  __bf16* ctx = kb;  // kb dead after projections

  cvt3_kernel<<<dim3(4096, 3), 256, 0, stream>>>(q, k, v, qb, kb, vb);
  cvt4_kernel<<<dim3(512, 4), 256, 0, stream>>>(Wq, Wk, Wv, Wo, wqb, wkb, wvb, wob);

  gemm_bt_kernel<__bf16>
      <<<dim3(64, 8, 3), 256, 0, stream>>>(qb, wqb, Qp, kb, wkb, Kp, vb, wvb, Vp);

  transpose_v<<<dim3(16, 16, 8), 256, 0, stream>>>(Vp, Vt);

  attn_fused_kernel<<<dim3(8, 128), 256, 0, stream>>>(Qp, Kp, Vt, attn, ctx);

  gemm_bt_kernel<float>
      <<<dim3(64, 8, 1), 256, 0, stream>>>(ctx, wob, out, ctx, wob, out, ctx, wob, out);
}